// Round 5
// baseline (261.457 us; speedup 1.0000x reference)
//
#include <hip/hip_runtime.h>

typedef _Float16 f16;
typedef f16 f16x8 __attribute__((ext_vector_type(8)));
typedef float f32x4 __attribute__((ext_vector_type(4)));

#define PI_F 3.14159265358979323846f

constexpr int TP = 128;          // points per block
constexpr int FSTR = 136;        // LDS row stride in f16 (272 B, 16B-aligned)
constexpr int PLANE_ELEMS = 128 * 128 * 16;   // per-plane f32 elems in the INPUT
constexpr int IPLANE = 128 * 128 * 32;        // interleaved f16 elems per axis
constexpr int ILINE = 128 * 32;               // interleaved f16 elems per axis

// ---------------------------------------------------------------------------
// Prep 1: fold basis into W1, f16 weights, interleave lines.
// Feature layout (96): [0..47] color plane*line products (axis-major, 16 ch)
//                      [48..50] ray, [51..86] enc (12d+6s+k), [87..95] 0
// ---------------------------------------------------------------------------
__global__ void prep_small(const float* __restrict__ W1, const float* __restrict__ basisW,
                           const float* __restrict__ W2, const float* __restrict__ W3,
                           const float* __restrict__ dlines, const float* __restrict__ clines,
                           f16* __restrict__ W1p, f16* __restrict__ W2h, f16* __restrict__ W3p,
                           f16* __restrict__ linesI) {
    int t = blockIdx.x * 256 + threadIdx.x;
    if (t < 128 * 96) {
        int r = t / 96, c = t % 96;
        float v = 0.f;
        if (c < 48) {
            for (int m = 0; m < 27; m++) v += W1[r * 66 + m] * basisW[m * 48 + c];
        } else if (c < 51) {
            v = W1[r * 66 + 27 + (c - 48)];
        } else if (c < 87) {
            v = W1[r * 66 + 30 + (c - 51)];
        }
        W1p[t] = (f16)v;
        return;
    }
    t -= 128 * 96;
    if (t < 128 * 128) { W2h[t] = (f16)W2[t]; return; }
    t -= 128 * 128;
    if (t < 16 * 128) {
        int r = t / 128, k = t % 128;
        W3p[t] = (f16)(r < 3 ? W3[r * 128 + k] : 0.f);
        return;
    }
    t -= 16 * 128;
    if (t < 3 * ILINE) {
        int axis = t / ILINE;
        int rem = t % ILINE;
        int l = rem / 32, c = rem % 32;
        float v = (c < 16) ? dlines[axis * 2048 + c * 128 + l]
                           : clines[axis * 2048 + (c - 16) * 128 + l];
        linesI[t] = (f16)v;
    }
}

// ---------------------------------------------------------------------------
// Prep 2: planes -> planesI f16 [axis][y][x][c32] (c<16 density, c>=16 color)
// ---------------------------------------------------------------------------
__global__ void interleave_planes(const float* __restrict__ dplanes,
                                  const float* __restrict__ cplanes,
                                  f16* __restrict__ planesI) {
    __shared__ f16 s[128 * 34];
    int b = blockIdx.x;
    int axis = b >> 7;
    int y = b & 127;
    const float* dsrc = dplanes + (size_t)axis * PLANE_ELEMS + y * 128;
    const float* csrc = cplanes + (size_t)axis * PLANE_ELEMS + y * 128;
    int tid = threadIdx.x;
#pragma unroll
    for (int it = 0; it < 8; it++) {
        int c = it * 2 + (tid >> 7);
        int x = tid & 127;
        s[x * 34 + c]      = (f16)dsrc[(size_t)c * 16384 + x];
        s[x * 34 + 16 + c] = (f16)csrc[(size_t)c * 16384 + x];
    }
    __syncthreads();
    f16* dst = planesI + (size_t)(axis * 128 + y) * (128 * 32);
#pragma unroll
    for (int it = 0; it < 8; it++) {
        int d = it * 256 + tid;
        int x = d >> 4, cp = (d & 15) * 2;
        dst[2 * d]     = s[x * 34 + cp];
        dst[2 * d + 1] = s[x * 34 + cp + 1];
    }
}

// shared coordinate/weight computation for one axis
struct AxisCoord {
    const f16 *c00, *c01, *c10, *c11, *l0, *l1;
    f16 w00, w01, w10, w11, wl1, wlh;
};

template <int I>
__device__ __forceinline__ AxisCoord axis_coord(const f16* __restrict__ planesI,
                                                const f16* __restrict__ linesI,
                                                const float* g) {
    constexpr int m0 = (I == 2) ? 1 : 0;
    constexpr int m1 = (I == 0) ? 1 : 2;
    constexpr int vm = 2 - I;
    float fx = (g[m0] + 1.f) * 0.5f * 127.f;
    float fy = (g[m1] + 1.f) * 0.5f * 127.f;
    float fl = (g[vm] + 1.f) * 0.5f * 127.f;
    int ix0 = min(max((int)floorf(fx), 0), 127); int ix1 = min(ix0 + 1, 127);
    int iy0 = min(max((int)floorf(fy), 0), 127); int iy1 = min(iy0 + 1, 127);
    int il0 = min(max((int)floorf(fl), 0), 127); int il1 = min(il0 + 1, 127);
    float wx = fx - (float)ix0, wy = fy - (float)iy0, wl = fl - (float)il0;
    AxisCoord a;
    a.w00 = (f16)((1.f - wx) * (1.f - wy));
    a.w01 = (f16)(wx * (1.f - wy));
    a.w10 = (f16)((1.f - wx) * wy);
    a.w11 = (f16)(wx * wy);
    a.wl1 = (f16)(1.f - wl); a.wlh = (f16)wl;
    a.c00 = planesI + ((I * 128 + iy0) * 128 + ix0) * 32;
    a.c01 = planesI + ((I * 128 + iy0) * 128 + ix1) * 32;
    a.c10 = planesI + ((I * 128 + iy1) * 128 + ix0) * 32;
    a.c11 = planesI + ((I * 128 + iy1) * 128 + ix1) * 32;
    a.l0 = linesI + (I * 128 + il0) * 32;
    a.l1 = linesI + (I * 128 + il1) * 32;
    return a;
}

// density half: channels q=0,1 (offsets 0,8) -> sigma partial
__device__ __forceinline__ float axis_density(const AxisCoord& a) {
    float sigma = 0.f;
#pragma unroll
    for (int q = 0; q < 2; q++) {
        f16x8 v00 = *(const f16x8*)(a.c00 + 8 * q);
        f16x8 v01 = *(const f16x8*)(a.c01 + 8 * q);
        f16x8 v10 = *(const f16x8*)(a.c10 + 8 * q);
        f16x8 v11 = *(const f16x8*)(a.c11 + 8 * q);
        f16x8 pb = v00 * a.w00 + v01 * a.w01 + v10 * a.w10 + v11 * a.w11;
        f16x8 lv = *(const f16x8*)(a.l0 + 8 * q) * a.wl1 + *(const f16x8*)(a.l1 + 8 * q) * a.wlh;
#pragma unroll
        for (int e = 0; e < 8; e++) sigma += (float)pb[e] * (float)lv[e];
    }
    return sigma;
}

// color half: channels q=2,3 (offsets 16,24) -> frow[16*I .. 16*I+15]
template <int I>
__device__ __forceinline__ void axis_color(const AxisCoord& a, f16* frow) {
#pragma unroll
    for (int qq = 0; qq < 2; qq++) {
        int q = 2 + qq;
        f16x8 v00 = *(const f16x8*)(a.c00 + 8 * q);
        f16x8 v01 = *(const f16x8*)(a.c01 + 8 * q);
        f16x8 v10 = *(const f16x8*)(a.c10 + 8 * q);
        f16x8 v11 = *(const f16x8*)(a.c11 + 8 * q);
        f16x8 pb = v00 * a.w00 + v01 * a.w01 + v10 * a.w10 + v11 * a.w11;
        f16x8 lv = *(const f16x8*)(a.l0 + 8 * q) * a.wl1 + *(const f16x8*)(a.l1 + 8 * q) * a.wlh;
        *(f16x8*)(frow + 16 * I + 8 * qq) = pb * lv;
    }
}

// ---------------------------------------------------------------------------
// Main fused kernel. 256 threads (4 waves), 128 points/block (34 KB LDS ->
// 4 blocks/CU = 16 waves/CU). Phase 1 splits each point across a WAVE pair:
// waves 0,1 (tid<128) = density+sigma; waves 2,3 = color+PE. Each wave is
// internally convergent (R4's lane-pair split was divergent -> 1.5x VALU).
// Phase 2: R2-proven two-n-chain MFMA MLP, m = 0..7.
// ---------------------------------------------------------------------------
__global__ __launch_bounds__(256, 4) void nerf_main(
    const float* __restrict__ pts, const float* __restrict__ rayu,
    const f16* __restrict__ planesI, const f16* __restrict__ linesI,
    const f16* __restrict__ W1p, const f16* __restrict__ W2h, const f16* __restrict__ W3p,
    const float* __restrict__ b1, const float* __restrict__ b2, const float* __restrict__ b3,
    float* __restrict__ out, int N) {
    __shared__ __align__(16) f16 tile[TP * FSTR];
    const int tid = threadIdx.x;
    const int role = tid >> 7;        // 0: density/sigma (waves 0,1), 1: color/PE (waves 2,3)
    const int pi = tid & 127;
    const int p0 = blockIdx.x * TP;
    const int p = p0 + pi;

    // ---------------- phase 1 ----------------
    if (role == 0) {
        float g[3] = {pts[3 * p + 0], pts[3 * p + 1], pts[3 * p + 2]};
        AxisCoord a0 = axis_coord<0>(planesI, linesI, g);
        AxisCoord a1 = axis_coord<1>(planesI, linesI, g);
        AxisCoord a2 = axis_coord<2>(planesI, linesI, g);
        float sigma = axis_density(a0) + axis_density(a1) + axis_density(a2);
        out[3 * N + p] = sigma;
    } else {
        float g[3] = {pts[3 * p + 0], pts[3 * p + 1], pts[3 * p + 2]};
        f16* frow = &tile[pi * FSTR];
        AxisCoord a0 = axis_coord<0>(planesI, linesI, g);
        axis_color<0>(a0, frow);
        AxisCoord a1 = axis_coord<1>(planesI, linesI, g);
        axis_color<1>(a1, frow);
        AxisCoord a2 = axis_coord<2>(planesI, linesI, g);
        axis_color<2>(a2, frow);
        float rx = rayu[3 * p + 0], ry = rayu[3 * p + 1], rz = rayu[3 * p + 2];
        float rv[3] = {rx, ry, rz};
        f16 tail[48];
        tail[0] = (f16)rx; tail[1] = (f16)ry; tail[2] = (f16)rz;
#pragma unroll
        for (int d = 0; d < 3; d++) {
            float f = rv[d] * PI_F;
            float s = __sinf(f), c = __cosf(f);
#pragma unroll
            for (int k = 0; k < 6; k++) {
                tail[3 + 12 * d + k] = (f16)s;
                tail[3 + 12 * d + 6 + k] = (f16)c;
                float ns = 2.f * s * c;
                float nc = 1.f - 2.f * s * s;
                s = ns; c = nc;
            }
        }
#pragma unroll
        for (int e = 39; e < 48; e++) tail[e] = (f16)0.f;
#pragma unroll
        for (int j = 0; j < 6; j++)
            *(f16x8*)&tile[pi * FSTR + 48 + 8 * j] = *(const f16x8*)&tail[8 * j];
    }
    __syncthreads();

    // ---------------- phase 2: MLP via MFMA ----------------
    const int w = tid >> 6, l = tid & 63, ar = l & 15, kg = l >> 4;
    const int col0 = 32 * w + ar;
    const int col1 = 32 * w + 16 + ar;

    f32x4 acc[8][2];

    // ---- L1: feat[128x96] @ W1p^T -> h1[128x128] ----
    {
        f16x8 bfr0[3], bfr1[3];
#pragma unroll
        for (int k = 0; k < 3; k++) {
            bfr0[k] = *(const f16x8*)(W1p + col0 * 96 + 32 * k + 8 * kg);
            bfr1[k] = *(const f16x8*)(W1p + col1 * 96 + 32 * k + 8 * kg);
        }
        float bias0 = b1[col0], bias1 = b1[col1];
#pragma unroll
        for (int m = 0; m < 8; m++) {
            acc[m][0] = (f32x4){bias0, bias0, bias0, bias0};
            acc[m][1] = (f32x4){bias1, bias1, bias1, bias1};
        }
#pragma unroll
        for (int m = 0; m < 8; m++) {
            const f16* arow = &tile[(16 * m + ar) * FSTR + 8 * kg];
#pragma unroll
            for (int k = 0; k < 3; k++) {
                f16x8 a = *(const f16x8*)(arow + 32 * k);
                acc[m][0] = __builtin_amdgcn_mfma_f32_16x16x32_f16(a, bfr0[k], acc[m][0], 0, 0, 0);
                acc[m][1] = __builtin_amdgcn_mfma_f32_16x16x32_f16(a, bfr1[k], acc[m][1], 0, 0, 0);
            }
        }
    }
    __syncthreads();
#pragma unroll
    for (int m = 0; m < 8; m++)
#pragma unroll
        for (int j = 0; j < 4; j++) {
            int row = 16 * m + 4 * kg + j;
            tile[row * FSTR + col0] = (f16)fmaxf(acc[m][0][j], 0.f);
            tile[row * FSTR + col1] = (f16)fmaxf(acc[m][1][j], 0.f);
        }
    __syncthreads();

    // ---- L2: h1[128x128] @ W2^T -> h2[128x128] ----
    {
        f16x8 bfr0[4], bfr1[4];
#pragma unroll
        for (int k = 0; k < 4; k++) {
            bfr0[k] = *(const f16x8*)(W2h + col0 * 128 + 32 * k + 8 * kg);
            bfr1[k] = *(const f16x8*)(W2h + col1 * 128 + 32 * k + 8 * kg);
        }
        float bias0 = b2[col0], bias1 = b2[col1];
#pragma unroll
        for (int m = 0; m < 8; m++) {
            acc[m][0] = (f32x4){bias0, bias0, bias0, bias0};
            acc[m][1] = (f32x4){bias1, bias1, bias1, bias1};
        }
#pragma unroll
        for (int m = 0; m < 8; m++) {
            const f16* arow = &tile[(16 * m + ar) * FSTR + 8 * kg];
#pragma unroll
            for (int k = 0; k < 4; k++) {
                f16x8 a = *(const f16x8*)(arow + 32 * k);
                acc[m][0] = __builtin_amdgcn_mfma_f32_16x16x32_f16(a, bfr0[k], acc[m][0], 0, 0, 0);
                acc[m][1] = __builtin_amdgcn_mfma_f32_16x16x32_f16(a, bfr1[k], acc[m][1], 0, 0, 0);
            }
        }
    }
    __syncthreads();
#pragma unroll
    for (int m = 0; m < 8; m++)
#pragma unroll
        for (int j = 0; j < 4; j++) {
            int row = 16 * m + 4 * kg + j;
            tile[row * FSTR + col0] = (f16)fmaxf(acc[m][0][j], 0.f);
            tile[row * FSTR + col1] = (f16)fmaxf(acc[m][1][j], 0.f);
        }
    __syncthreads();

    // ---- L3: h2[128x128] @ W3p^T -> rgb; each wave does 2 m-tiles ----
    {
        f16x8 bfr[4];
#pragma unroll
        for (int k = 0; k < 4; k++)
            bfr[k] = *(const f16x8*)(W3p + ar * 128 + 32 * k + 8 * kg);
        float bias3 = (ar < 3) ? b3[ar] : 0.f;
#pragma unroll
        for (int mm = 0; mm < 2; mm++) {
            int m = 2 * w + mm;
            f32x4 a3 = (f32x4){bias3, bias3, bias3, bias3};
#pragma unroll
            for (int k = 0; k < 4; k++) {
                f16x8 a = *(const f16x8*)&tile[(16 * m + ar) * FSTR + 32 * k + 8 * kg];
                a3 = __builtin_amdgcn_mfma_f32_16x16x32_f16(a, bfr[k], a3, 0, 0, 0);
            }
            if (ar < 3) {
#pragma unroll
                for (int j = 0; j < 4; j++) {
                    int row = p0 + 16 * m + 4 * kg + j;
                    out[3 * row + ar] = 1.f / (1.f + __expf(-a3[j]));
                }
            }
        }
    }
}

extern "C" void kernel_launch(void* const* d_in, const int* in_sizes, int n_in,
                              void* d_out, int out_size, void* d_ws, size_t ws_size,
                              hipStream_t stream) {
    const float* pts    = (const float*)d_in[0];
    const float* rayu   = (const float*)d_in[1];
    const float* dplanes = (const float*)d_in[2];
    const float* dlines  = (const float*)d_in[3];
    const float* cplanes = (const float*)d_in[4];
    const float* clines  = (const float*)d_in[5];
    const float* basisW  = (const float*)d_in[6];
    const float* W1 = (const float*)d_in[7];
    const float* b1 = (const float*)d_in[8];
    const float* W2 = (const float*)d_in[9];
    const float* b2 = (const float*)d_in[10];
    const float* W3 = (const float*)d_in[11];
    const float* b3 = (const float*)d_in[12];
    float* out = (float*)d_out;
    const int N = in_sizes[0] / 3;

    f16* planesI = (f16*)d_ws;                 // 3 * 128*128*32
    f16* linesI = planesI + 3 * IPLANE;        // 3 * 128*32
    f16* W1p = linesI + 3 * ILINE;             // 128*96
    f16* W2h = W1p + 128 * 96;                 // 128*128
    f16* W3p = W2h + 128 * 128;                // 16*128

    prep_small<<<168, 256, 0, stream>>>(W1, basisW, W2, W3, dlines, clines,
                                        W1p, W2h, W3p, linesI);
    interleave_planes<<<384, 256, 0, stream>>>(dplanes, cplanes, planesI);
    nerf_main<<<N / TP, 256, 0, stream>>>(pts, rayu, planesI, linesI,
                                          W1p, W2h, W3p, b1, b2, b3, out, N);
}

// Round 6
// 156.068 us; speedup vs baseline: 1.6753x; 1.6753x over previous
//
#include <hip/hip_runtime.h>

typedef _Float16 f16;
typedef f16 f16x8 __attribute__((ext_vector_type(8)));
typedef f16 f16x2 __attribute__((ext_vector_type(2)));
typedef float f32x4 __attribute__((ext_vector_type(4)));

#define PI_F 3.14159265358979323846f

constexpr int TP = 256;          // points per block
constexpr int FSTR = 136;        // LDS row stride in f16 (272 B, 16B-aligned)
constexpr int PLANE_ELEMS = 128 * 128 * 16;   // per-plane f32 elems in the INPUT
constexpr int IPLANE = 128 * 128 * 32;        // interleaved f16 elems per axis
constexpr int ILINE = 128 * 32;               // interleaved f16 elems per axis

// ---------------------------------------------------------------------------
// Prep 1: fold basis into W1, f16 weights, interleave lines.
// Feature layout (96): [0..47] color plane*line products (axis-major, 16 ch)
//                      [48..50] ray, [51..86] enc, [87..95] 0
// ---------------------------------------------------------------------------
__global__ void prep_small(const float* __restrict__ W1, const float* __restrict__ basisW,
                           const float* __restrict__ W2, const float* __restrict__ W3,
                           const float* __restrict__ dlines, const float* __restrict__ clines,
                           f16* __restrict__ W1p, f16* __restrict__ W2h, f16* __restrict__ W3p,
                           f16* __restrict__ linesI) {
    int t = blockIdx.x * 256 + threadIdx.x;
    if (t < 128 * 96) {
        int r = t / 96, c = t % 96;
        float v = 0.f;
        if (c < 48) {
            for (int m = 0; m < 27; m++) v += W1[r * 66 + m] * basisW[m * 48 + c];
        } else if (c < 51) {
            v = W1[r * 66 + 27 + (c - 48)];
        } else if (c < 87) {
            v = W1[r * 66 + 30 + (c - 51)];
        }
        W1p[t] = (f16)v;
        return;
    }
    t -= 128 * 96;
    if (t < 128 * 128) { W2h[t] = (f16)W2[t]; return; }
    t -= 128 * 128;
    if (t < 16 * 128) {
        int r = t / 128, k = t % 128;
        W3p[t] = (f16)(r < 3 ? W3[r * 128 + k] : 0.f);
        return;
    }
    t -= 16 * 128;
    if (t < 3 * ILINE) {
        int axis = t / ILINE;
        int rem = t % ILINE;
        int l = rem / 32, c = rem % 32;
        float v = (c < 16) ? dlines[axis * 2048 + c * 128 + l]
                           : clines[axis * 2048 + (c - 16) * 128 + l];
        linesI[t] = (f16)v;
    }
}

// ---------------------------------------------------------------------------
// Prep 2: planes -> planesI f16 [axis][y][x][c32] (c<16 density, c>=16 color)
// ---------------------------------------------------------------------------
__global__ void interleave_planes(const float* __restrict__ dplanes,
                                  const float* __restrict__ cplanes,
                                  f16* __restrict__ planesI) {
    __shared__ f16 s[128 * 34];
    int b = blockIdx.x;
    int axis = b >> 7;
    int y = b & 127;
    const float* dsrc = dplanes + (size_t)axis * PLANE_ELEMS + y * 128;
    const float* csrc = cplanes + (size_t)axis * PLANE_ELEMS + y * 128;
    int tid = threadIdx.x;
#pragma unroll
    for (int it = 0; it < 8; it++) {
        int c = it * 2 + (tid >> 7);
        int x = tid & 127;
        s[x * 34 + c]      = (f16)dsrc[(size_t)c * 16384 + x];
        s[x * 34 + 16 + c] = (f16)csrc[(size_t)c * 16384 + x];
    }
    __syncthreads();
    f16* dst = planesI + (size_t)(axis * 128 + y) * (128 * 32);
#pragma unroll
    for (int it = 0; it < 8; it++) {
        int d = it * 256 + tid;
        int x = d >> 4, cp = (d & 15) * 2;
        dst[2 * d]     = s[x * 34 + cp];
        dst[2 * d + 1] = s[x * 34 + cp + 1];
    }
}

// ---------------------------------------------------------------------------
// Main fused kernel. 256 threads (4 waves), 256 points/block (R2 geometry).
// Phase 1a: cooperative gather — 4 lanes per point, lane q owns 16B chunk q
//   of every 64B texel (q=0,1: density -> sigma; q=2,3: color -> LDS feat).
//   One load instruction = 16 points x 4 coalescing lanes = 16 L1 txns
//   instead of 64 (the R2 bottleneck).
// Phase 1b: PE, 1 thread per point (pure VALU, no duplication).
// Phase 2: R2-proven two-n-chain MFMA MLP (verbatim).
// ---------------------------------------------------------------------------
__global__ __launch_bounds__(256, 2) void nerf_main(
    const float* __restrict__ pts, const float* __restrict__ rayu,
    const f16* __restrict__ planesI, const f16* __restrict__ linesI,
    const f16* __restrict__ W1p, const f16* __restrict__ W2h, const f16* __restrict__ W3p,
    const float* __restrict__ b1, const float* __restrict__ b2, const float* __restrict__ b3,
    float* __restrict__ out, int N) {
    __shared__ __align__(16) f16 tile[TP * FSTR];
    const int tid = threadIdx.x;
    const int p0 = blockIdx.x * TP;

    // ---------------- phase 1a: cooperative texture gather ----------------
    {
        const int grp = tid >> 2;      // 64 groups; group g handles points it*64+g
        const int q = tid & 3;         // 16B chunk owned by this lane
        const int qc = q - 2;          // color chunk index for q=2,3
#pragma unroll
        for (int it = 0; it < 4; it++) {
            const int pi = it * 64 + grp;
            const int pp = p0 + pi;
            float g0 = pts[3 * pp + 0], g1 = pts[3 * pp + 1], g2 = pts[3 * pp + 2];
            float g[3] = {g0, g1, g2};
            float sigma = 0.f;
            f16* frow = &tile[pi * FSTR];
#pragma unroll
            for (int i = 0; i < 3; i++) {
                const int m0 = (i == 2) ? 1 : 0;
                const int m1 = (i == 0) ? 1 : 2;
                const int vm = 2 - i;
                float fx = (g[m0] + 1.f) * 0.5f * 127.f;
                float fy = (g[m1] + 1.f) * 0.5f * 127.f;
                float fl = (g[vm] + 1.f) * 0.5f * 127.f;
                int ix0 = min(max((int)floorf(fx), 0), 127); int ix1 = min(ix0 + 1, 127);
                int iy0 = min(max((int)floorf(fy), 0), 127); int iy1 = min(iy0 + 1, 127);
                int il0 = min(max((int)floorf(fl), 0), 127); int il1 = min(il0 + 1, 127);
                float wx = fx - (float)ix0, wy = fy - (float)iy0, wl = fl - (float)il0;
                f16 w00 = (f16)((1.f - wx) * (1.f - wy));
                f16 w01 = (f16)(wx * (1.f - wy));
                f16 w10 = (f16)((1.f - wx) * wy);
                f16 w11 = (f16)(wx * wy);
                f16 wl1 = (f16)(1.f - wl), wlh = (f16)wl;
                // lane's 16B chunk of each 64B texel
                const f16* c00 = planesI + ((i * 128 + iy0) * 128 + ix0) * 32 + 8 * q;
                const f16* c01 = planesI + ((i * 128 + iy0) * 128 + ix1) * 32 + 8 * q;
                const f16* c10 = planesI + ((i * 128 + iy1) * 128 + ix0) * 32 + 8 * q;
                const f16* c11 = planesI + ((i * 128 + iy1) * 128 + ix1) * 32 + 8 * q;
                const f16* l0 = linesI + (i * 128 + il0) * 32 + 8 * q;
                const f16* l1 = linesI + (i * 128 + il1) * 32 + 8 * q;
                f16x8 v00 = *(const f16x8*)c00;
                f16x8 v01 = *(const f16x8*)c01;
                f16x8 v10 = *(const f16x8*)c10;
                f16x8 v11 = *(const f16x8*)c11;
                f16x8 pb = v00 * w00 + v01 * w01 + v10 * w10 + v11 * w11;
                f16x8 lv = *(const f16x8*)l0 * wl1 + *(const f16x8*)l1 * wlh;
                f16x8 prod = pb * lv;
                if (q < 2) {
                    const f16x2 one2 = {(f16)1.f, (f16)1.f};
#pragma unroll
                    for (int e = 0; e < 4; e++) {
                        f16x2 pr2 = {prod[2 * e], prod[2 * e + 1]};
                        sigma = __builtin_amdgcn_fdot2(pr2, one2, sigma, false);
                    }
                } else {
                    *(f16x8*)(frow + 16 * i + 8 * qc) = prod;
                }
            }
            sigma += __shfl_xor(sigma, 1);   // lanes 0+1 of each group
            if (q == 0) out[3 * N + pp] = sigma;
        }
    }

    // ---------------- phase 1b: PE + ray, one thread per point ----------------
    {
        const int pp = p0 + tid;
        float rx = rayu[3 * pp + 0], ry = rayu[3 * pp + 1], rz = rayu[3 * pp + 2];
        float rv[3] = {rx, ry, rz};
        f16 tail[48];
        tail[0] = (f16)rx; tail[1] = (f16)ry; tail[2] = (f16)rz;
#pragma unroll
        for (int d = 0; d < 3; d++) {
            float f = rv[d] * PI_F;
            float s = __sinf(f), c = __cosf(f);
#pragma unroll
            for (int k = 0; k < 6; k++) {
                tail[3 + 12 * d + k] = (f16)s;
                tail[3 + 12 * d + 6 + k] = (f16)c;
                float ns = 2.f * s * c;
                float nc = 1.f - 2.f * s * s;
                s = ns; c = nc;
            }
        }
#pragma unroll
        for (int e = 39; e < 48; e++) tail[e] = (f16)0.f;
#pragma unroll
        for (int j = 0; j < 6; j++)
            *(f16x8*)&tile[tid * FSTR + 48 + 8 * j] = *(const f16x8*)&tail[8 * j];
    }
    __syncthreads();

    // ---------------- phase 2: MLP via MFMA (R2 verbatim) ----------------
    const int w = tid >> 6, l = tid & 63, ar = l & 15, kg = l >> 4;
    const int col0 = 32 * w + ar;
    const int col1 = 32 * w + 16 + ar;

    f32x4 acc[16][2];

    // ---- L1: feat[256x96] @ W1p^T -> h1[256x128] ----
    {
        f16x8 bfr0[3], bfr1[3];
#pragma unroll
        for (int k = 0; k < 3; k++) {
            bfr0[k] = *(const f16x8*)(W1p + col0 * 96 + 32 * k + 8 * kg);
            bfr1[k] = *(const f16x8*)(W1p + col1 * 96 + 32 * k + 8 * kg);
        }
        float bias0 = b1[col0], bias1 = b1[col1];
#pragma unroll
        for (int m = 0; m < 16; m++) {
            acc[m][0] = (f32x4){bias0, bias0, bias0, bias0};
            acc[m][1] = (f32x4){bias1, bias1, bias1, bias1};
        }
#pragma unroll
        for (int m = 0; m < 16; m++) {
            const f16* arow = &tile[(16 * m + ar) * FSTR + 8 * kg];
#pragma unroll
            for (int k = 0; k < 3; k++) {
                f16x8 a = *(const f16x8*)(arow + 32 * k);
                acc[m][0] = __builtin_amdgcn_mfma_f32_16x16x32_f16(a, bfr0[k], acc[m][0], 0, 0, 0);
                acc[m][1] = __builtin_amdgcn_mfma_f32_16x16x32_f16(a, bfr1[k], acc[m][1], 0, 0, 0);
            }
        }
    }
    __syncthreads();
#pragma unroll
    for (int m = 0; m < 16; m++)
#pragma unroll
        for (int j = 0; j < 4; j++) {
            int row = 16 * m + 4 * kg + j;
            tile[row * FSTR + col0] = (f16)fmaxf(acc[m][0][j], 0.f);
            tile[row * FSTR + col1] = (f16)fmaxf(acc[m][1][j], 0.f);
        }
    __syncthreads();

    // ---- L2: h1[256x128] @ W2^T -> h2[256x128] ----
    {
        f16x8 bfr0[4], bfr1[4];
#pragma unroll
        for (int k = 0; k < 4; k++) {
            bfr0[k] = *(const f16x8*)(W2h + col0 * 128 + 32 * k + 8 * kg);
            bfr1[k] = *(const f16x8*)(W2h + col1 * 128 + 32 * k + 8 * kg);
        }
        float bias0 = b2[col0], bias1 = b2[col1];
#pragma unroll
        for (int m = 0; m < 16; m++) {
            acc[m][0] = (f32x4){bias0, bias0, bias0, bias0};
            acc[m][1] = (f32x4){bias1, bias1, bias1, bias1};
        }
#pragma unroll
        for (int m = 0; m < 16; m++) {
            const f16* arow = &tile[(16 * m + ar) * FSTR + 8 * kg];
#pragma unroll
            for (int k = 0; k < 4; k++) {
                f16x8 a = *(const f16x8*)(arow + 32 * k);
                acc[m][0] = __builtin_amdgcn_mfma_f32_16x16x32_f16(a, bfr0[k], acc[m][0], 0, 0, 0);
                acc[m][1] = __builtin_amdgcn_mfma_f32_16x16x32_f16(a, bfr1[k], acc[m][1], 0, 0, 0);
            }
        }
    }
    __syncthreads();
#pragma unroll
    for (int m = 0; m < 16; m++)
#pragma unroll
        for (int j = 0; j < 4; j++) {
            int row = 16 * m + 4 * kg + j;
            tile[row * FSTR + col0] = (f16)fmaxf(acc[m][0][j], 0.f);
            tile[row * FSTR + col1] = (f16)fmaxf(acc[m][1][j], 0.f);
        }
    __syncthreads();

    // ---- L3: h2[256x128] @ W3p^T -> rgb ----
    {
        f16x8 bfr[4];
#pragma unroll
        for (int k = 0; k < 4; k++)
            bfr[k] = *(const f16x8*)(W3p + ar * 128 + 32 * k + 8 * kg);
        float bias3 = (ar < 3) ? b3[ar] : 0.f;
#pragma unroll
        for (int mm = 0; mm < 4; mm++) {
            int m = 4 * w + mm;
            f32x4 a3 = (f32x4){bias3, bias3, bias3, bias3};
#pragma unroll
            for (int k = 0; k < 4; k++) {
                f16x8 a = *(const f16x8*)&tile[(16 * m + ar) * FSTR + 32 * k + 8 * kg];
                a3 = __builtin_amdgcn_mfma_f32_16x16x32_f16(a, bfr[k], a3, 0, 0, 0);
            }
            if (ar < 3) {
#pragma unroll
                for (int j = 0; j < 4; j++) {
                    int row = p0 + 16 * m + 4 * kg + j;
                    out[3 * row + ar] = 1.f / (1.f + __expf(-a3[j]));
                }
            }
        }
    }
}

extern "C" void kernel_launch(void* const* d_in, const int* in_sizes, int n_in,
                              void* d_out, int out_size, void* d_ws, size_t ws_size,
                              hipStream_t stream) {
    const float* pts    = (const float*)d_in[0];
    const float* rayu   = (const float*)d_in[1];
    const float* dplanes = (const float*)d_in[2];
    const float* dlines  = (const float*)d_in[3];
    const float* cplanes = (const float*)d_in[4];
    const float* clines  = (const float*)d_in[5];
    const float* basisW  = (const float*)d_in[6];
    const float* W1 = (const float*)d_in[7];
    const float* b1 = (const float*)d_in[8];
    const float* W2 = (const float*)d_in[9];
    const float* b2 = (const float*)d_in[10];
    const float* W3 = (const float*)d_in[11];
    const float* b3 = (const float*)d_in[12];
    float* out = (float*)d_out;
    const int N = in_sizes[0] / 3;

    f16* planesI = (f16*)d_ws;                 // 3 * 128*128*32
    f16* linesI = planesI + 3 * IPLANE;        // 3 * 128*32
    f16* W1p = linesI + 3 * ILINE;             // 128*96
    f16* W2h = W1p + 128 * 96;                 // 128*128
    f16* W3p = W2h + 128 * 128;                // 16*128

    prep_small<<<168, 256, 0, stream>>>(W1, basisW, W2, W3, dlines, clines,
                                        W1p, W2h, W3p, linesI);
    interleave_planes<<<384, 256, 0, stream>>>(dplanes, cplanes, planesI);
    nerf_main<<<N / TP, 256, 0, stream>>>(pts, rayu, planesI, linesI,
                                          W1p, W2h, W3p, b1, b2, b3, out, N);
}

// Round 7
// 141.768 us; speedup vs baseline: 1.8443x; 1.1009x over previous
//
#include <hip/hip_runtime.h>

typedef _Float16 f16;
typedef f16 f16x8 __attribute__((ext_vector_type(8)));
typedef f16 f16x2 __attribute__((ext_vector_type(2)));
typedef float f32x4 __attribute__((ext_vector_type(4)));

#define PI_F 3.14159265358979323846f

constexpr int TP = 128;          // points per block
constexpr int FSTR = 136;        // LDS row stride in f16 (272 B, 16B-aligned)
constexpr int PLANE_ELEMS = 128 * 128 * 16;   // per-plane f32 elems in the INPUT
constexpr int IPLANE = 128 * 128 * 32;        // interleaved f16 elems per axis
constexpr int ILINE = 128 * 32;               // interleaved f16 elems per axis

// ---------------------------------------------------------------------------
// Prep 1: fold basis into W1, f16 weights, interleave lines.
// Feature layout (96): [0..47] color plane*line products (axis-major, 16 ch)
//                      [48..50] ray, [51..86] enc, [87..95] 0
// ---------------------------------------------------------------------------
__global__ void prep_small(const float* __restrict__ W1, const float* __restrict__ basisW,
                           const float* __restrict__ W2, const float* __restrict__ W3,
                           const float* __restrict__ dlines, const float* __restrict__ clines,
                           f16* __restrict__ W1p, f16* __restrict__ W2h, f16* __restrict__ W3p,
                           f16* __restrict__ linesI) {
    int t = blockIdx.x * 256 + threadIdx.x;
    if (t < 128 * 96) {
        int r = t / 96, c = t % 96;
        float v = 0.f;
        if (c < 48) {
            for (int m = 0; m < 27; m++) v += W1[r * 66 + m] * basisW[m * 48 + c];
        } else if (c < 51) {
            v = W1[r * 66 + 27 + (c - 48)];
        } else if (c < 87) {
            v = W1[r * 66 + 30 + (c - 51)];
        }
        W1p[t] = (f16)v;
        return;
    }
    t -= 128 * 96;
    if (t < 128 * 128) { W2h[t] = (f16)W2[t]; return; }
    t -= 128 * 128;
    if (t < 16 * 128) {
        int r = t / 128, k = t % 128;
        W3p[t] = (f16)(r < 3 ? W3[r * 128 + k] : 0.f);
        return;
    }
    t -= 16 * 128;
    if (t < 3 * ILINE) {
        int axis = t / ILINE;
        int rem = t % ILINE;
        int l = rem / 32, c = rem % 32;
        float v = (c < 16) ? dlines[axis * 2048 + c * 128 + l]
                           : clines[axis * 2048 + (c - 16) * 128 + l];
        linesI[t] = (f16)v;
    }
}

// ---------------------------------------------------------------------------
// Prep 2: planes -> planesI f16 [axis][y][x][c32] (c<16 density, c>=16 color)
// ---------------------------------------------------------------------------
__global__ void interleave_planes(const float* __restrict__ dplanes,
                                  const float* __restrict__ cplanes,
                                  f16* __restrict__ planesI) {
    __shared__ f16 s[128 * 34];
    int b = blockIdx.x;
    int axis = b >> 7;
    int y = b & 127;
    const float* dsrc = dplanes + (size_t)axis * PLANE_ELEMS + y * 128;
    const float* csrc = cplanes + (size_t)axis * PLANE_ELEMS + y * 128;
    int tid = threadIdx.x;
#pragma unroll
    for (int it = 0; it < 8; it++) {
        int c = it * 2 + (tid >> 7);
        int x = tid & 127;
        s[x * 34 + c]      = (f16)dsrc[(size_t)c * 16384 + x];
        s[x * 34 + 16 + c] = (f16)csrc[(size_t)c * 16384 + x];
    }
    __syncthreads();
    f16* dst = planesI + (size_t)(axis * 128 + y) * (128 * 32);
#pragma unroll
    for (int it = 0; it < 8; it++) {
        int d = it * 256 + tid;
        int x = d >> 4, cp = (d & 15) * 2;
        dst[2 * d]     = s[x * 34 + cp];
        dst[2 * d + 1] = s[x * 34 + cp + 1];
    }
}

// ---------------------------------------------------------------------------
// Main fused kernel. 256 threads (4 waves), 128 points/block, 34 KB LDS ->
// 4 blocks/CU = 16 waves/CU (R4 geometry, proven 43% occupancy).
// Phase 1a: R6-proven cooperative gather — 4 lanes per point, lane q owns
//   16B chunk q of every 64B texel (q=0,1: density -> sigma; q=2,3: color).
// Phase 1b: PE, 1 thread per point (tid<128; waves 2,3 idle briefly).
// Phase 2: R4-proven two-n-chain MFMA MLP, m = 0..7.
// ---------------------------------------------------------------------------
__global__ __launch_bounds__(256, 4) void nerf_main(
    const float* __restrict__ pts, const float* __restrict__ rayu,
    const f16* __restrict__ planesI, const f16* __restrict__ linesI,
    const f16* __restrict__ W1p, const f16* __restrict__ W2h, const f16* __restrict__ W3p,
    const float* __restrict__ b1, const float* __restrict__ b2, const float* __restrict__ b3,
    float* __restrict__ out, int N) {
    __shared__ __align__(16) f16 tile[TP * FSTR];
    const int tid = threadIdx.x;
    const int p0 = blockIdx.x * TP;

    // ---------------- phase 1a: cooperative texture gather ----------------
    {
        const int grp = tid >> 2;      // 64 groups; group g handles points it*64+g
        const int q = tid & 3;         // 16B chunk owned by this lane
        const int qc = q - 2;          // color chunk index for q=2,3
#pragma unroll
        for (int it = 0; it < 2; it++) {
            const int pi = it * 64 + grp;
            const int pp = p0 + pi;
            float g0 = pts[3 * pp + 0], g1 = pts[3 * pp + 1], g2 = pts[3 * pp + 2];
            float g[3] = {g0, g1, g2};
            float sigma = 0.f;
            f16* frow = &tile[pi * FSTR];
#pragma unroll
            for (int i = 0; i < 3; i++) {
                const int m0 = (i == 2) ? 1 : 0;
                const int m1 = (i == 0) ? 1 : 2;
                const int vm = 2 - i;
                float fx = (g[m0] + 1.f) * 0.5f * 127.f;
                float fy = (g[m1] + 1.f) * 0.5f * 127.f;
                float fl = (g[vm] + 1.f) * 0.5f * 127.f;
                int ix0 = min(max((int)floorf(fx), 0), 127); int ix1 = min(ix0 + 1, 127);
                int iy0 = min(max((int)floorf(fy), 0), 127); int iy1 = min(iy0 + 1, 127);
                int il0 = min(max((int)floorf(fl), 0), 127); int il1 = min(il0 + 1, 127);
                float wx = fx - (float)ix0, wy = fy - (float)iy0, wl = fl - (float)il0;
                f16 w00 = (f16)((1.f - wx) * (1.f - wy));
                f16 w01 = (f16)(wx * (1.f - wy));
                f16 w10 = (f16)((1.f - wx) * wy);
                f16 w11 = (f16)(wx * wy);
                f16 wl1 = (f16)(1.f - wl), wlh = (f16)wl;
                const f16* c00 = planesI + ((i * 128 + iy0) * 128 + ix0) * 32 + 8 * q;
                const f16* c01 = planesI + ((i * 128 + iy0) * 128 + ix1) * 32 + 8 * q;
                const f16* c10 = planesI + ((i * 128 + iy1) * 128 + ix0) * 32 + 8 * q;
                const f16* c11 = planesI + ((i * 128 + iy1) * 128 + ix1) * 32 + 8 * q;
                const f16* l0 = linesI + (i * 128 + il0) * 32 + 8 * q;
                const f16* l1 = linesI + (i * 128 + il1) * 32 + 8 * q;
                f16x8 v00 = *(const f16x8*)c00;
                f16x8 v01 = *(const f16x8*)c01;
                f16x8 v10 = *(const f16x8*)c10;
                f16x8 v11 = *(const f16x8*)c11;
                f16x8 pb = v00 * w00 + v01 * w01 + v10 * w10 + v11 * w11;
                f16x8 lv = *(const f16x8*)l0 * wl1 + *(const f16x8*)l1 * wlh;
                f16x8 prod = pb * lv;
                if (q < 2) {
                    const f16x2 one2 = {(f16)1.f, (f16)1.f};
#pragma unroll
                    for (int e = 0; e < 4; e++) {
                        f16x2 pr2 = {prod[2 * e], prod[2 * e + 1]};
                        sigma = __builtin_amdgcn_fdot2(pr2, one2, sigma, false);
                    }
                } else {
                    *(f16x8*)(frow + 16 * i + 8 * qc) = prod;
                }
            }
            sigma += __shfl_xor(sigma, 1);   // lanes 0+1 of each group
            if (q == 0) out[3 * N + pp] = sigma;
        }
    }

    // ---------------- phase 1b: PE + ray, one thread per point ----------------
    if (tid < TP) {
        const int pp = p0 + tid;
        float rx = rayu[3 * pp + 0], ry = rayu[3 * pp + 1], rz = rayu[3 * pp + 2];
        float rv[3] = {rx, ry, rz};
        f16 tail[48];
        tail[0] = (f16)rx; tail[1] = (f16)ry; tail[2] = (f16)rz;
#pragma unroll
        for (int d = 0; d < 3; d++) {
            float f = rv[d] * PI_F;
            float s = __sinf(f), c = __cosf(f);
#pragma unroll
            for (int k = 0; k < 6; k++) {
                tail[3 + 12 * d + k] = (f16)s;
                tail[3 + 12 * d + 6 + k] = (f16)c;
                float ns = 2.f * s * c;
                float nc = 1.f - 2.f * s * s;
                s = ns; c = nc;
            }
        }
#pragma unroll
        for (int e = 39; e < 48; e++) tail[e] = (f16)0.f;
#pragma unroll
        for (int j = 0; j < 6; j++)
            *(f16x8*)&tile[tid * FSTR + 48 + 8 * j] = *(const f16x8*)&tail[8 * j];
    }
    __syncthreads();

    // ---------------- phase 2: MLP via MFMA ----------------
    const int w = tid >> 6, l = tid & 63, ar = l & 15, kg = l >> 4;
    const int col0 = 32 * w + ar;
    const int col1 = 32 * w + 16 + ar;

    f32x4 acc[8][2];

    // ---- L1: feat[128x96] @ W1p^T -> h1[128x128] ----
    {
        f16x8 bfr0[3], bfr1[3];
#pragma unroll
        for (int k = 0; k < 3; k++) {
            bfr0[k] = *(const f16x8*)(W1p + col0 * 96 + 32 * k + 8 * kg);
            bfr1[k] = *(const f16x8*)(W1p + col1 * 96 + 32 * k + 8 * kg);
        }
        float bias0 = b1[col0], bias1 = b1[col1];
#pragma unroll
        for (int m = 0; m < 8; m++) {
            acc[m][0] = (f32x4){bias0, bias0, bias0, bias0};
            acc[m][1] = (f32x4){bias1, bias1, bias1, bias1};
        }
#pragma unroll
        for (int m = 0; m < 8; m++) {
            const f16* arow = &tile[(16 * m + ar) * FSTR + 8 * kg];
#pragma unroll
            for (int k = 0; k < 3; k++) {
                f16x8 a = *(const f16x8*)(arow + 32 * k);
                acc[m][0] = __builtin_amdgcn_mfma_f32_16x16x32_f16(a, bfr0[k], acc[m][0], 0, 0, 0);
                acc[m][1] = __builtin_amdgcn_mfma_f32_16x16x32_f16(a, bfr1[k], acc[m][1], 0, 0, 0);
            }
        }
    }
    __syncthreads();
#pragma unroll
    for (int m = 0; m < 8; m++)
#pragma unroll
        for (int j = 0; j < 4; j++) {
            int row = 16 * m + 4 * kg + j;
            tile[row * FSTR + col0] = (f16)fmaxf(acc[m][0][j], 0.f);
            tile[row * FSTR + col1] = (f16)fmaxf(acc[m][1][j], 0.f);
        }
    __syncthreads();

    // ---- L2: h1[128x128] @ W2^T -> h2[128x128] ----
    {
        f16x8 bfr0[4], bfr1[4];
#pragma unroll
        for (int k = 0; k < 4; k++) {
            bfr0[k] = *(const f16x8*)(W2h + col0 * 128 + 32 * k + 8 * kg);
            bfr1[k] = *(const f16x8*)(W2h + col1 * 128 + 32 * k + 8 * kg);
        }
        float bias0 = b2[col0], bias1 = b2[col1];
#pragma unroll
        for (int m = 0; m < 8; m++) {
            acc[m][0] = (f32x4){bias0, bias0, bias0, bias0};
            acc[m][1] = (f32x4){bias1, bias1, bias1, bias1};
        }
#pragma unroll
        for (int m = 0; m < 8; m++) {
            const f16* arow = &tile[(16 * m + ar) * FSTR + 8 * kg];
#pragma unroll
            for (int k = 0; k < 4; k++) {
                f16x8 a = *(const f16x8*)(arow + 32 * k);
                acc[m][0] = __builtin_amdgcn_mfma_f32_16x16x32_f16(a, bfr0[k], acc[m][0], 0, 0, 0);
                acc[m][1] = __builtin_amdgcn_mfma_f32_16x16x32_f16(a, bfr1[k], acc[m][1], 0, 0, 0);
            }
        }
    }
    __syncthreads();
#pragma unroll
    for (int m = 0; m < 8; m++)
#pragma unroll
        for (int j = 0; j < 4; j++) {
            int row = 16 * m + 4 * kg + j;
            tile[row * FSTR + col0] = (f16)fmaxf(acc[m][0][j], 0.f);
            tile[row * FSTR + col1] = (f16)fmaxf(acc[m][1][j], 0.f);
        }
    __syncthreads();

    // ---- L3: h2[128x128] @ W3p^T -> rgb; each wave does 2 m-tiles ----
    {
        f16x8 bfr[4];
#pragma unroll
        for (int k = 0; k < 4; k++)
            bfr[k] = *(const f16x8*)(W3p + ar * 128 + 32 * k + 8 * kg);
        float bias3 = (ar < 3) ? b3[ar] : 0.f;
#pragma unroll
        for (int mm = 0; mm < 2; mm++) {
            int m = 2 * w + mm;
            f32x4 a3 = (f32x4){bias3, bias3, bias3, bias3};
#pragma unroll
            for (int k = 0; k < 4; k++) {
                f16x8 a = *(const f16x8*)&tile[(16 * m + ar) * FSTR + 32 * k + 8 * kg];
                a3 = __builtin_amdgcn_mfma_f32_16x16x32_f16(a, bfr[k], a3, 0, 0, 0);
            }
            if (ar < 3) {
#pragma unroll
                for (int j = 0; j < 4; j++) {
                    int row = p0 + 16 * m + 4 * kg + j;
                    out[3 * row + ar] = 1.f / (1.f + __expf(-a3[j]));
                }
            }
        }
    }
}

extern "C" void kernel_launch(void* const* d_in, const int* in_sizes, int n_in,
                              void* d_out, int out_size, void* d_ws, size_t ws_size,
                              hipStream_t stream) {
    const float* pts    = (const float*)d_in[0];
    const float* rayu   = (const float*)d_in[1];
    const float* dplanes = (const float*)d_in[2];
    const float* dlines  = (const float*)d_in[3];
    const float* cplanes = (const float*)d_in[4];
    const float* clines  = (const float*)d_in[5];
    const float* basisW  = (const float*)d_in[6];
    const float* W1 = (const float*)d_in[7];
    const float* b1 = (const float*)d_in[8];
    const float* W2 = (const float*)d_in[9];
    const float* b2 = (const float*)d_in[10];
    const float* W3 = (const float*)d_in[11];
    const float* b3 = (const float*)d_in[12];
    float* out = (float*)d_out;
    const int N = in_sizes[0] / 3;

    f16* planesI = (f16*)d_ws;                 // 3 * 128*128*32
    f16* linesI = planesI + 3 * IPLANE;        // 3 * 128*32
    f16* W1p = linesI + 3 * ILINE;             // 128*96
    f16* W2h = W1p + 128 * 96;                 // 128*128
    f16* W3p = W2h + 128 * 128;                // 16*128

    prep_small<<<168, 256, 0, stream>>>(W1, basisW, W2, W3, dlines, clines,
                                        W1p, W2h, W3p, linesI);
    interleave_planes<<<384, 256, 0, stream>>>(dplanes, cplanes, planesI);
    nerf_main<<<N / TP, 256, 0, stream>>>(pts, rayu, planesI, linesI,
                                          W1p, W2h, W3p, b1, b2, b3, out, N);
}

// Round 9
// 136.606 us; speedup vs baseline: 1.9140x; 1.0378x over previous
//
#include <hip/hip_runtime.h>

typedef _Float16 f16;
typedef f16 f16x8 __attribute__((ext_vector_type(8)));
typedef f16 f16x2 __attribute__((ext_vector_type(2)));
typedef __fp16 h16x2 __attribute__((ext_vector_type(2)));   // cvt_pkrtz return type
typedef float f32x4 __attribute__((ext_vector_type(4)));

#define PI_F 3.14159265358979323846f

constexpr int TP = 128;          // points per block
constexpr int FSTR = 136;        // LDS row stride in f16 (272 B, 16B-aligned)
constexpr int PLANE_ELEMS = 128 * 128 * 16;   // per-plane f32 elems in the INPUT
constexpr int IPLANE = 128 * 128 * 32;        // interleaved f16 elems per axis
constexpr int ILINE = 128 * 32;               // interleaved f16 elems per axis

// h-tile column packing: within each 32-col block, logical col c is stored at
// p(c) = 2*(c&15) + (c>>4).  Inverse: k = (s>>1) + 16*(s&1)  (within block).
// Lets a lane pack its (col, col+16) pair into one cvt_pkrtz + ds_write_b32.
// W2h / W3p K-columns are permuted identically in prep.

// ---------------------------------------------------------------------------
// Prep 1: fold basis into W1, f16 weights (W2/W3 K-permuted), interleave lines.
// Feature layout (96): [0..47] color plane*line products (axis-major, 16 ch)
//                      [48..50] ray, [51..86] enc, [87..95] 0
// ---------------------------------------------------------------------------
__global__ void prep_small(const float* __restrict__ W1, const float* __restrict__ basisW,
                           const float* __restrict__ W2, const float* __restrict__ W3,
                           const float* __restrict__ dlines, const float* __restrict__ clines,
                           f16* __restrict__ W1p, f16* __restrict__ W2h, f16* __restrict__ W3p,
                           f16* __restrict__ linesI) {
    int t = blockIdx.x * 256 + threadIdx.x;
    if (t < 128 * 96) {
        int r = t / 96, c = t % 96;
        float v = 0.f;
        if (c < 48) {
            for (int m = 0; m < 27; m++) v += W1[r * 66 + m] * basisW[m * 48 + c];
        } else if (c < 51) {
            v = W1[r * 66 + 27 + (c - 48)];
        } else if (c < 87) {
            v = W1[r * 66 + 30 + (c - 51)];
        }
        W1p[t] = (f16)v;
        return;
    }
    t -= 128 * 96;
    if (t < 128 * 128) {
        int n = t / 128, s = t % 128;
        int k = (s & ~31) + ((s & 31) >> 1) + 16 * (s & 1);   // inverse perm
        W2h[t] = (f16)W2[n * 128 + k];
        return;
    }
    t -= 128 * 128;
    if (t < 16 * 128) {
        int r = t / 128, s = t % 128;
        int k = (s & ~31) + ((s & 31) >> 1) + 16 * (s & 1);
        W3p[t] = (f16)(r < 3 ? W3[r * 128 + k] : 0.f);
        return;
    }
    t -= 16 * 128;
    if (t < 3 * ILINE) {
        int axis = t / ILINE;
        int rem = t % ILINE;
        int l = rem / 32, c = rem % 32;
        float v = (c < 16) ? dlines[axis * 2048 + c * 128 + l]
                           : clines[axis * 2048 + (c - 16) * 128 + l];
        linesI[t] = (f16)v;
    }
}

// ---------------------------------------------------------------------------
// Prep 2: planes -> planesI f16 [axis][y][x][c32] (c<16 density, c>=16 color)
// ---------------------------------------------------------------------------
__global__ void interleave_planes(const float* __restrict__ dplanes,
                                  const float* __restrict__ cplanes,
                                  f16* __restrict__ planesI) {
    __shared__ f16 s[128 * 34];
    int b = blockIdx.x;
    int axis = b >> 7;
    int y = b & 127;
    const float* dsrc = dplanes + (size_t)axis * PLANE_ELEMS + y * 128;
    const float* csrc = cplanes + (size_t)axis * PLANE_ELEMS + y * 128;
    int tid = threadIdx.x;
#pragma unroll
    for (int it = 0; it < 8; it++) {
        int c = it * 2 + (tid >> 7);
        int x = tid & 127;
        s[x * 34 + c]      = (f16)dsrc[(size_t)c * 16384 + x];
        s[x * 34 + 16 + c] = (f16)csrc[(size_t)c * 16384 + x];
    }
    __syncthreads();
    f16* dst = planesI + (size_t)(axis * 128 + y) * (128 * 32);
#pragma unroll
    for (int it = 0; it < 8; it++) {
        int d = it * 256 + tid;
        int x = d >> 4, cp = (d & 15) * 2;
        dst[2 * d]     = s[x * 34 + cp];
        dst[2 * d + 1] = s[x * 34 + cp + 1];
    }
}

// ---------------------------------------------------------------------------
// Main fused kernel. 256 threads (4 waves), 128 points/block, 34 KB LDS ->
// 4 blocks/CU (40% occ, R7-proven).
// Phase 1a: cooperative gather (R6-proven), single-base addressing:
//   g in [-1,1] -> fx in [0,127]; ix0=min((int)fx,126); ix1=ix0+1 in-bounds.
// Phase 1b: PE, 1 thread per point.
// Phase 2: MFMA MLP with PACKED h-writeback (cvt_pkrtz + ds_write_b32),
//   h stored column-interleaved, W2h/W3p K-permuted to match.
// ---------------------------------------------------------------------------
__global__ __launch_bounds__(256, 4) void nerf_main(
    const float* __restrict__ pts, const float* __restrict__ rayu,
    const f16* __restrict__ planesI, const f16* __restrict__ linesI,
    const f16* __restrict__ W1p, const f16* __restrict__ W2h, const f16* __restrict__ W3p,
    const float* __restrict__ b1, const float* __restrict__ b2, const float* __restrict__ b3,
    float* __restrict__ out, int N) {
    __shared__ __align__(16) f16 tile[TP * FSTR];
    const int tid = threadIdx.x;
    const int p0 = blockIdx.x * TP;

    // ---------------- phase 1a: cooperative texture gather ----------------
    {
        const int grp = tid >> 2;      // 64 groups; group g handles points it*64+g
        const int q = tid & 3;         // 16B chunk owned by this lane
        const int qc = q - 2;          // color chunk index for q=2,3
        const f16* pq = planesI + 8 * q;
        const f16* lq = linesI + 8 * q;
#pragma unroll
        for (int it = 0; it < 2; it++) {
            const int pi = it * 64 + grp;
            const int pp = p0 + pi;
            float g0 = pts[3 * pp + 0], g1 = pts[3 * pp + 1], g2 = pts[3 * pp + 2];
            float g[3] = {g0, g1, g2};
            float sigma = 0.f;
            f16* frow = &tile[pi * FSTR];
#pragma unroll
            for (int i = 0; i < 3; i++) {
                const int m0 = (i == 2) ? 1 : 0;
                const int m1 = (i == 0) ? 1 : 2;
                const int vm = 2 - i;
                float fx = (g[m0] + 1.f) * 63.5f;
                float fy = (g[m1] + 1.f) * 63.5f;
                float fl = (g[vm] + 1.f) * 63.5f;
                int ix0 = min((int)fx, 126);
                int iy0 = min((int)fy, 126);
                int il0 = min((int)fl, 126);
                float wx = fx - (float)ix0, wy = fy - (float)iy0, wl = fl - (float)il0;
                f16 w00 = (f16)((1.f - wx) * (1.f - wy));
                f16 w01 = (f16)(wx * (1.f - wy));
                f16 w10 = (f16)((1.f - wx) * wy);
                f16 w11 = (f16)(wx * wy);
                f16 wl1 = (f16)(1.f - wl), wlh = (f16)wl;
                const f16* c00 = pq + ((i * 128 + iy0) * 128 + ix0) * 32;
                const f16* c10 = c00 + 128 * 32;
                const f16* l0 = lq + (i * 128 + il0) * 32;
                f16x8 v00 = *(const f16x8*)c00;
                f16x8 v01 = *(const f16x8*)(c00 + 32);
                f16x8 v10 = *(const f16x8*)c10;
                f16x8 v11 = *(const f16x8*)(c10 + 32);
                f16x8 pb = v00 * w00 + v01 * w01 + v10 * w10 + v11 * w11;
                f16x8 lv = *(const f16x8*)l0 * wl1 + *(const f16x8*)(l0 + 32) * wlh;
                f16x8 prod = pb * lv;
                if (q < 2) {
                    const f16x2 one2 = {(f16)1.f, (f16)1.f};
#pragma unroll
                    for (int e = 0; e < 4; e++) {
                        f16x2 pr2 = {prod[2 * e], prod[2 * e + 1]};
                        sigma = __builtin_amdgcn_fdot2(pr2, one2, sigma, false);
                    }
                } else {
                    *(f16x8*)(frow + 16 * i + 8 * qc) = prod;
                }
            }
            sigma += __shfl_xor(sigma, 1);   // lanes 0+1 of each group
            if (q == 0) out[3 * N + pp] = sigma;
        }
    }

    // ---------------- phase 1b: PE + ray, one thread per point ----------------
    if (tid < TP) {
        const int pp = p0 + tid;
        float rx = rayu[3 * pp + 0], ry = rayu[3 * pp + 1], rz = rayu[3 * pp + 2];
        float rv[3] = {rx, ry, rz};
        f16 tail[48];
        tail[0] = (f16)rx; tail[1] = (f16)ry; tail[2] = (f16)rz;
#pragma unroll
        for (int d = 0; d < 3; d++) {
            float f = rv[d] * PI_F;
            float s = __sinf(f), c = __cosf(f);
#pragma unroll
            for (int k = 0; k < 6; k++) {
                tail[3 + 12 * d + k] = (f16)s;
                tail[3 + 12 * d + 6 + k] = (f16)c;
                float ns = 2.f * s * c;
                float nc = 1.f - 2.f * s * s;
                s = ns; c = nc;
            }
        }
#pragma unroll
        for (int e = 39; e < 48; e++) tail[e] = (f16)0.f;
#pragma unroll
        for (int j = 0; j < 6; j++)
            *(f16x8*)&tile[tid * FSTR + 48 + 8 * j] = *(const f16x8*)&tail[8 * j];
    }
    __syncthreads();

    // ---------------- phase 2: MLP via MFMA ----------------
    const int w = tid >> 6, l = tid & 63, ar = l & 15, kg = l >> 4;
    const int col0 = 32 * w + ar;          // logical output cols
    const int col1 = 32 * w + 16 + ar;
    const int wbo = 32 * w + 2 * ar;       // packed writeback f16 offset in row

    f32x4 acc[8][2];

    // ---- L1: feat[128x96] @ W1p^T -> h1[128x128] (packed store) ----
    {
        f16x8 bfr0[3], bfr1[3];
#pragma unroll
        for (int k = 0; k < 3; k++) {
            bfr0[k] = *(const f16x8*)(W1p + col0 * 96 + 32 * k + 8 * kg);
            bfr1[k] = *(const f16x8*)(W1p + col1 * 96 + 32 * k + 8 * kg);
        }
        float bias0 = b1[col0], bias1 = b1[col1];
#pragma unroll
        for (int m = 0; m < 8; m++) {
            acc[m][0] = (f32x4){bias0, bias0, bias0, bias0};
            acc[m][1] = (f32x4){bias1, bias1, bias1, bias1};
        }
#pragma unroll
        for (int m = 0; m < 8; m++) {
            const f16* arow = &tile[(16 * m + ar) * FSTR + 8 * kg];
#pragma unroll
            for (int k = 0; k < 3; k++) {
                f16x8 a = *(const f16x8*)(arow + 32 * k);
                acc[m][0] = __builtin_amdgcn_mfma_f32_16x16x32_f16(a, bfr0[k], acc[m][0], 0, 0, 0);
                acc[m][1] = __builtin_amdgcn_mfma_f32_16x16x32_f16(a, bfr1[k], acc[m][1], 0, 0, 0);
            }
        }
    }
    __syncthreads();
#pragma unroll
    for (int m = 0; m < 8; m++)
#pragma unroll
        for (int j = 0; j < 4; j++) {
            int row = 16 * m + 4 * kg + j;
            h16x2 pr = __builtin_amdgcn_cvt_pkrtz(fmaxf(acc[m][0][j], 0.f),
                                                  fmaxf(acc[m][1][j], 0.f));
            *(h16x2*)&tile[row * FSTR + wbo] = pr;
        }
    __syncthreads();

    // ---- L2: h1[128x128] @ W2^T -> h2[128x128] (packed, W2h K-permuted) ----
    {
        f16x8 bfr0[4], bfr1[4];
#pragma unroll
        for (int k = 0; k < 4; k++) {
            bfr0[k] = *(const f16x8*)(W2h + col0 * 128 + 32 * k + 8 * kg);
            bfr1[k] = *(const f16x8*)(W2h + col1 * 128 + 32 * k + 8 * kg);
        }
        float bias0 = b2[col0], bias1 = b2[col1];
#pragma unroll
        for (int m = 0; m < 8; m++) {
            acc[m][0] = (f32x4){bias0, bias0, bias0, bias0};
            acc[m][1] = (f32x4){bias1, bias1, bias1, bias1};
        }
#pragma unroll
        for (int m = 0; m < 8; m++) {
            const f16* arow = &tile[(16 * m + ar) * FSTR + 8 * kg];
#pragma unroll
            for (int k = 0; k < 4; k++) {
                f16x8 a = *(const f16x8*)(arow + 32 * k);
                acc[m][0] = __builtin_amdgcn_mfma_f32_16x16x32_f16(a, bfr0[k], acc[m][0], 0, 0, 0);
                acc[m][1] = __builtin_amdgcn_mfma_f32_16x16x32_f16(a, bfr1[k], acc[m][1], 0, 0, 0);
            }
        }
    }
    __syncthreads();
#pragma unroll
    for (int m = 0; m < 8; m++)
#pragma unroll
        for (int j = 0; j < 4; j++) {
            int row = 16 * m + 4 * kg + j;
            h16x2 pr = __builtin_amdgcn_cvt_pkrtz(fmaxf(acc[m][0][j], 0.f),
                                                  fmaxf(acc[m][1][j], 0.f));
            *(h16x2*)&tile[row * FSTR + wbo] = pr;
        }
    __syncthreads();

    // ---- L3: h2[128x128] @ W3p^T -> rgb (W3p K-permuted); 2 m-tiles/wave ----
    {
        f16x8 bfr[4];
#pragma unroll
        for (int k = 0; k < 4; k++)
            bfr[k] = *(const f16x8*)(W3p + ar * 128 + 32 * k + 8 * kg);
        float bias3 = (ar < 3) ? b3[ar] : 0.f;
#pragma unroll
        for (int mm = 0; mm < 2; mm++) {
            int m = 2 * w + mm;
            f32x4 a3 = (f32x4){bias3, bias3, bias3, bias3};
#pragma unroll
            for (int k = 0; k < 4; k++) {
                f16x8 a = *(const f16x8*)&tile[(16 * m + ar) * FSTR + 32 * k + 8 * kg];
                a3 = __builtin_amdgcn_mfma_f32_16x16x32_f16(a, bfr[k], a3, 0, 0, 0);
            }
            if (ar < 3) {
#pragma unroll
                for (int j = 0; j < 4; j++) {
                    int row = p0 + 16 * m + 4 * kg + j;
                    out[3 * row + ar] = 1.f / (1.f + __expf(-a3[j]));
                }
            }
        }
    }
}

extern "C" void kernel_launch(void* const* d_in, const int* in_sizes, int n_in,
                              void* d_out, int out_size, void* d_ws, size_t ws_size,
                              hipStream_t stream) {
    const float* pts    = (const float*)d_in[0];
    const float* rayu   = (const float*)d_in[1];
    const float* dplanes = (const float*)d_in[2];
    const float* dlines  = (const float*)d_in[3];
    const float* cplanes = (const float*)d_in[4];
    const float* clines  = (const float*)d_in[5];
    const float* basisW  = (const float*)d_in[6];
    const float* W1 = (const float*)d_in[7];
    const float* b1 = (const float*)d_in[8];
    const float* W2 = (const float*)d_in[9];
    const float* b2 = (const float*)d_in[10];
    const float* W3 = (const float*)d_in[11];
    const float* b3 = (const float*)d_in[12];
    float* out = (float*)d_out;
    const int N = in_sizes[0] / 3;

    f16* planesI = (f16*)d_ws;                 // 3 * 128*128*32
    f16* linesI = planesI + 3 * IPLANE;        // 3 * 128*32
    f16* W1p = linesI + 3 * ILINE;             // 128*96
    f16* W2h = W1p + 128 * 96;                 // 128*128 (K-permuted)
    f16* W3p = W2h + 128 * 128;                // 16*128  (K-permuted)

    prep_small<<<168, 256, 0, stream>>>(W1, basisW, W2, W3, dlines, clines,
                                        W1p, W2h, W3p, linesI);
    interleave_planes<<<384, 256, 0, stream>>>(dplanes, cplanes, planesI);
    nerf_main<<<N / TP, 256, 0, stream>>>(pts, rayu, planesI, linesI,
                                          W1p, W2h, W3p, b1, b2, b3, out, N);
}

// Round 10
// 129.059 us; speedup vs baseline: 2.0259x; 1.0585x over previous
//
#include <hip/hip_runtime.h>

typedef _Float16 f16;
typedef f16 f16x8 __attribute__((ext_vector_type(8)));
typedef f16 f16x2 __attribute__((ext_vector_type(2)));
typedef __fp16 h16x2 __attribute__((ext_vector_type(2)));   // cvt_pkrtz return type
typedef float f32x4 __attribute__((ext_vector_type(4)));

#define PI_F 3.14159265358979323846f

constexpr int TP = 128;          // points per block
constexpr int FSTR = 136;        // LDS row stride in f16 (272 B, 16B-aligned)
constexpr int PLANE_ELEMS = 128 * 128 * 16;   // per-plane f32 elems in the INPUT
constexpr int IPLANE = 128 * 128 * 32;        // interleaved f16 elems per axis
constexpr int ILINE = 128 * 32;               // interleaved f16 elems per axis

// h-tile column packing: within each 32-col block, logical col c stored at
// p(c) = 2*(c&15) + (c>>4); W2h/W3p K-columns permuted identically in prep.

// ---------------------------------------------------------------------------
// Prep 1: fold basis into W1, f16 weights (W2/W3 K-permuted), interleave lines.
// ---------------------------------------------------------------------------
__global__ void prep_small(const float* __restrict__ W1, const float* __restrict__ basisW,
                           const float* __restrict__ W2, const float* __restrict__ W3,
                           const float* __restrict__ dlines, const float* __restrict__ clines,
                           f16* __restrict__ W1p, f16* __restrict__ W2h, f16* __restrict__ W3p,
                           f16* __restrict__ linesI) {
    int t = blockIdx.x * 256 + threadIdx.x;
    if (t < 128 * 96) {
        int r = t / 96, c = t % 96;
        float v = 0.f;
        if (c < 48) {
            for (int m = 0; m < 27; m++) v += W1[r * 66 + m] * basisW[m * 48 + c];
        } else if (c < 51) {
            v = W1[r * 66 + 27 + (c - 48)];
        } else if (c < 87) {
            v = W1[r * 66 + 30 + (c - 51)];
        }
        W1p[t] = (f16)v;
        return;
    }
    t -= 128 * 96;
    if (t < 128 * 128) {
        int n = t / 128, s = t % 128;
        int k = (s & ~31) + ((s & 31) >> 1) + 16 * (s & 1);   // inverse perm
        W2h[t] = (f16)W2[n * 128 + k];
        return;
    }
    t -= 128 * 128;
    if (t < 16 * 128) {
        int r = t / 128, s = t % 128;
        int k = (s & ~31) + ((s & 31) >> 1) + 16 * (s & 1);
        W3p[t] = (f16)(r < 3 ? W3[r * 128 + k] : 0.f);
        return;
    }
    t -= 16 * 128;
    if (t < 3 * ILINE) {
        int axis = t / ILINE;
        int rem = t % ILINE;
        int l = rem / 32, c = rem % 32;
        float v = (c < 16) ? dlines[axis * 2048 + c * 128 + l]
                           : clines[axis * 2048 + (c - 16) * 128 + l];
        linesI[t] = (f16)v;
    }
}

// ---------------------------------------------------------------------------
// Prep 2: planes -> planesI f16 [axis][y][x][c32] (c<16 density, c>=16 color)
// ---------------------------------------------------------------------------
__global__ void interleave_planes(const float* __restrict__ dplanes,
                                  const float* __restrict__ cplanes,
                                  f16* __restrict__ planesI) {
    __shared__ f16 s[128 * 34];
    int b = blockIdx.x;
    int axis = b >> 7;
    int y = b & 127;
    const float* dsrc = dplanes + (size_t)axis * PLANE_ELEMS + y * 128;
    const float* csrc = cplanes + (size_t)axis * PLANE_ELEMS + y * 128;
    int tid = threadIdx.x;
#pragma unroll
    for (int it = 0; it < 8; it++) {
        int c = it * 2 + (tid >> 7);
        int x = tid & 127;
        s[x * 34 + c]      = (f16)dsrc[(size_t)c * 16384 + x];
        s[x * 34 + 16 + c] = (f16)csrc[(size_t)c * 16384 + x];
    }
    __syncthreads();
    f16* dst = planesI + (size_t)(axis * 128 + y) * (128 * 32);
#pragma unroll
    for (int it = 0; it < 8; it++) {
        int d = it * 256 + tid;
        int x = d >> 4, cp = (d & 15) * 2;
        dst[2 * d]     = s[x * 34 + cp];
        dst[2 * d + 1] = s[x * 34 + cp + 1];
    }
}

// ---------------------------------------------------------------------------
// Main fused kernel. 256 threads / 128 points / 34 KB LDS -> 4 blocks/CU.
// Phase 1a: cooperative gather (4 lanes/point, 16B chunk each).
// Phase 1b: PE on tid<128.
// Phase 2: MFMA MLP, k-OUTER loops over 4-m blocks (8 independent MFMA
//   chains, hides ~16cy MFMA latency), B-fragments prefetched a phase early
//   (latency hidden under gather / writeback barriers).
// ---------------------------------------------------------------------------
__global__ __launch_bounds__(256, 4) void nerf_main(
    const float* __restrict__ pts, const float* __restrict__ rayu,
    const f16* __restrict__ planesI, const f16* __restrict__ linesI,
    const f16* __restrict__ W1p, const f16* __restrict__ W2h, const f16* __restrict__ W3p,
    const float* __restrict__ b1, const float* __restrict__ b2, const float* __restrict__ b3,
    float* __restrict__ out, int N) {
    __shared__ __align__(16) f16 tile[TP * FSTR];
    const int tid = threadIdx.x;
    const int p0 = blockIdx.x * TP;

    // lane mapping for phase 2 (needed for prefetch addressing)
    const int w = tid >> 6, l = tid & 63, ar = l & 15, kg = l >> 4;
    const int col0 = 32 * w + ar;
    const int col1 = 32 * w + 16 + ar;
    const int wbo = 32 * w + 2 * ar;

    // ---- prefetch L1 B-fragments + biases (completes during gather) ----
    f16x8 w1f0[3], w1f1[3];
#pragma unroll
    for (int k = 0; k < 3; k++) {
        w1f0[k] = *(const f16x8*)(W1p + col0 * 96 + 32 * k + 8 * kg);
        w1f1[k] = *(const f16x8*)(W1p + col1 * 96 + 32 * k + 8 * kg);
    }
    const float bias1_0 = b1[col0], bias1_1 = b1[col1];
    const float bias2_0 = b2[col0], bias2_1 = b2[col1];
    const float bias3v = (ar < 3) ? b3[ar] : 0.f;

    // ---------------- phase 1a: cooperative texture gather ----------------
    {
        const int grp = tid >> 2;
        const int q = tid & 3;
        const int qc = q - 2;
        const f16* pq = planesI + 8 * q;
        const f16* lq = linesI + 8 * q;
#pragma unroll
        for (int it = 0; it < 2; it++) {
            const int pi = it * 64 + grp;
            const int pp = p0 + pi;
            float g0 = pts[3 * pp + 0], g1 = pts[3 * pp + 1], g2 = pts[3 * pp + 2];
            float g[3] = {g0, g1, g2};
            float sigma = 0.f;
            f16* frow = &tile[pi * FSTR];
#pragma unroll
            for (int i = 0; i < 3; i++) {
                const int m0 = (i == 2) ? 1 : 0;
                const int m1 = (i == 0) ? 1 : 2;
                const int vm = 2 - i;
                float fx = (g[m0] + 1.f) * 63.5f;
                float fy = (g[m1] + 1.f) * 63.5f;
                float fl = (g[vm] + 1.f) * 63.5f;
                int ix0 = min((int)fx, 126);
                int iy0 = min((int)fy, 126);
                int il0 = min((int)fl, 126);
                float wx = fx - (float)ix0, wy = fy - (float)iy0, wl = fl - (float)il0;
                f16 w00 = (f16)((1.f - wx) * (1.f - wy));
                f16 w01 = (f16)(wx * (1.f - wy));
                f16 w10 = (f16)((1.f - wx) * wy);
                f16 w11 = (f16)(wx * wy);
                f16 wl1 = (f16)(1.f - wl), wlh = (f16)wl;
                const f16* c00 = pq + ((i * 128 + iy0) * 128 + ix0) * 32;
                const f16* c10 = c00 + 128 * 32;
                const f16* l0 = lq + (i * 128 + il0) * 32;
                f16x8 v00 = *(const f16x8*)c00;
                f16x8 v01 = *(const f16x8*)(c00 + 32);
                f16x8 v10 = *(const f16x8*)c10;
                f16x8 v11 = *(const f16x8*)(c10 + 32);
                f16x8 pb = v00 * w00 + v01 * w01 + v10 * w10 + v11 * w11;
                f16x8 lv = *(const f16x8*)l0 * wl1 + *(const f16x8*)(l0 + 32) * wlh;
                f16x8 prod = pb * lv;
                if (q < 2) {
                    const f16x2 one2 = {(f16)1.f, (f16)1.f};
#pragma unroll
                    for (int e = 0; e < 4; e++) {
                        f16x2 pr2 = {prod[2 * e], prod[2 * e + 1]};
                        sigma = __builtin_amdgcn_fdot2(pr2, one2, sigma, false);
                    }
                } else {
                    *(f16x8*)(frow + 16 * i + 8 * qc) = prod;
                }
            }
            sigma += __shfl_xor(sigma, 1);
            if (q == 0) out[3 * N + pp] = sigma;
        }
    }

    // ---------------- phase 1b: PE + ray, one thread per point ----------------
    if (tid < TP) {
        const int pp = p0 + tid;
        float rx = rayu[3 * pp + 0], ry = rayu[3 * pp + 1], rz = rayu[3 * pp + 2];
        float rv[3] = {rx, ry, rz};
        f16 tail[48];
        tail[0] = (f16)rx; tail[1] = (f16)ry; tail[2] = (f16)rz;
#pragma unroll
        for (int d = 0; d < 3; d++) {
            float f = rv[d] * PI_F;
            float s = __sinf(f), c = __cosf(f);
#pragma unroll
            for (int k = 0; k < 6; k++) {
                tail[3 + 12 * d + k] = (f16)s;
                tail[3 + 12 * d + 6 + k] = (f16)c;
                float ns = 2.f * s * c;
                float nc = 1.f - 2.f * s * s;
                s = ns; c = nc;
            }
        }
#pragma unroll
        for (int e = 39; e < 48; e++) tail[e] = (f16)0.f;
#pragma unroll
        for (int j = 0; j < 6; j++)
            *(f16x8*)&tile[tid * FSTR + 48 + 8 * j] = *(const f16x8*)&tail[8 * j];
    }
    __syncthreads();

    // ---------------- phase 2: MLP via MFMA ----------------
    f32x4 acc[8][2];

    // ---- L1: feat[128x96] @ W1p^T -> h1 (k-outer, 8 indep chains) ----
#pragma unroll
    for (int m = 0; m < 8; m++) {
        acc[m][0] = (f32x4){bias1_0, bias1_0, bias1_0, bias1_0};
        acc[m][1] = (f32x4){bias1_1, bias1_1, bias1_1, bias1_1};
    }
#pragma unroll
    for (int mb = 0; mb < 2; mb++) {
#pragma unroll
        for (int k = 0; k < 3; k++) {
            f16x8 a[4];
#pragma unroll
            for (int mm = 0; mm < 4; mm++)
                a[mm] = *(const f16x8*)&tile[(16 * (4 * mb + mm) + ar) * FSTR + 32 * k + 8 * kg];
#pragma unroll
            for (int mm = 0; mm < 4; mm++) {
                int m = 4 * mb + mm;
                acc[m][0] = __builtin_amdgcn_mfma_f32_16x16x32_f16(a[mm], w1f0[k], acc[m][0], 0, 0, 0);
                acc[m][1] = __builtin_amdgcn_mfma_f32_16x16x32_f16(a[mm], w1f1[k], acc[m][1], 0, 0, 0);
            }
        }
    }

    // prefetch L2 B-fragments (latency hidden under writeback barriers)
    f16x8 w2f0[4], w2f1[4];
#pragma unroll
    for (int k = 0; k < 4; k++) {
        w2f0[k] = *(const f16x8*)(W2h + col0 * 128 + 32 * k + 8 * kg);
        w2f1[k] = *(const f16x8*)(W2h + col1 * 128 + 32 * k + 8 * kg);
    }

    __syncthreads();
#pragma unroll
    for (int m = 0; m < 8; m++)
#pragma unroll
        for (int j = 0; j < 4; j++) {
            int row = 16 * m + 4 * kg + j;
            h16x2 pr = __builtin_amdgcn_cvt_pkrtz(fmaxf(acc[m][0][j], 0.f),
                                                  fmaxf(acc[m][1][j], 0.f));
            *(h16x2*)&tile[row * FSTR + wbo] = pr;
        }
    __syncthreads();

    // ---- L2: h1[128x128] @ W2^T -> h2 (k-outer) ----
#pragma unroll
    for (int m = 0; m < 8; m++) {
        acc[m][0] = (f32x4){bias2_0, bias2_0, bias2_0, bias2_0};
        acc[m][1] = (f32x4){bias2_1, bias2_1, bias2_1, bias2_1};
    }
#pragma unroll
    for (int mb = 0; mb < 2; mb++) {
#pragma unroll
        for (int k = 0; k < 4; k++) {
            f16x8 a[4];
#pragma unroll
            for (int mm = 0; mm < 4; mm++)
                a[mm] = *(const f16x8*)&tile[(16 * (4 * mb + mm) + ar) * FSTR + 32 * k + 8 * kg];
#pragma unroll
            for (int mm = 0; mm < 4; mm++) {
                int m = 4 * mb + mm;
                acc[m][0] = __builtin_amdgcn_mfma_f32_16x16x32_f16(a[mm], w2f0[k], acc[m][0], 0, 0, 0);
                acc[m][1] = __builtin_amdgcn_mfma_f32_16x16x32_f16(a[mm], w2f1[k], acc[m][1], 0, 0, 0);
            }
        }
    }

    // prefetch L3 B-fragments
    f16x8 w3f[4];
#pragma unroll
    for (int k = 0; k < 4; k++)
        w3f[k] = *(const f16x8*)(W3p + ar * 128 + 32 * k + 8 * kg);

    __syncthreads();
#pragma unroll
    for (int m = 0; m < 8; m++)
#pragma unroll
        for (int j = 0; j < 4; j++) {
            int row = 16 * m + 4 * kg + j;
            h16x2 pr = __builtin_amdgcn_cvt_pkrtz(fmaxf(acc[m][0][j], 0.f),
                                                  fmaxf(acc[m][1][j], 0.f));
            *(h16x2*)&tile[row * FSTR + wbo] = pr;
        }
    __syncthreads();

    // ---- L3: h2[128x128] @ W3p^T -> rgb (k-outer, 2 chains) ----
    {
        f32x4 a3[2];
#pragma unroll
        for (int mm = 0; mm < 2; mm++) a3[mm] = (f32x4){bias3v, bias3v, bias3v, bias3v};
#pragma unroll
        for (int k = 0; k < 4; k++) {
#pragma unroll
            for (int mm = 0; mm < 2; mm++) {
                int m = 2 * w + mm;
                f16x8 a = *(const f16x8*)&tile[(16 * m + ar) * FSTR + 32 * k + 8 * kg];
                a3[mm] = __builtin_amdgcn_mfma_f32_16x16x32_f16(a, w3f[k], a3[mm], 0, 0, 0);
            }
        }
        if (ar < 3) {
#pragma unroll
            for (int mm = 0; mm < 2; mm++) {
                int m = 2 * w + mm;
#pragma unroll
                for (int j = 0; j < 4; j++) {
                    int row = p0 + 16 * m + 4 * kg + j;
                    out[3 * row + ar] = 1.f / (1.f + __expf(-a3[mm][j]));
                }
            }
        }
    }
}

extern "C" void kernel_launch(void* const* d_in, const int* in_sizes, int n_in,
                              void* d_out, int out_size, void* d_ws, size_t ws_size,
                              hipStream_t stream) {
    const float* pts    = (const float*)d_in[0];
    const float* rayu   = (const float*)d_in[1];
    const float* dplanes = (const float*)d_in[2];
    const float* dlines  = (const float*)d_in[3];
    const float* cplanes = (const float*)d_in[4];
    const float* clines  = (const float*)d_in[5];
    const float* basisW  = (const float*)d_in[6];
    const float* W1 = (const float*)d_in[7];
    const float* b1 = (const float*)d_in[8];
    const float* W2 = (const float*)d_in[9];
    const float* b2 = (const float*)d_in[10];
    const float* W3 = (const float*)d_in[11];
    const float* b3 = (const float*)d_in[12];
    float* out = (float*)d_out;
    const int N = in_sizes[0] / 3;

    f16* planesI = (f16*)d_ws;                 // 3 * 128*128*32
    f16* linesI = planesI + 3 * IPLANE;        // 3 * 128*32
    f16* W1p = linesI + 3 * ILINE;             // 128*96
    f16* W2h = W1p + 128 * 96;                 // 128*128 (K-permuted)
    f16* W3p = W2h + 128 * 128;                // 16*128  (K-permuted)

    prep_small<<<168, 256, 0, stream>>>(W1, basisW, W2, W3, dlines, clines,
                                        W1p, W2h, W3p, linesI);
    interleave_planes<<<384, 256, 0, stream>>>(dplanes, cplanes, planesI);
    nerf_main<<<N / TP, 256, 0, stream>>>(pts, rayu, planesI, linesI,
                                          W1p, W2h, W3p, b1, b2, b3, out, N);
}